// Round 2
// baseline (132.646 us; speedup 1.0000x reference)
//
#include <hip/hip_runtime.h>
#include <hip/hip_bf16.h>

typedef __attribute__((ext_vector_type(8))) short short8;
typedef __attribute__((ext_vector_type(4))) float floatx4;

#define D_DIM 128
#define SCALE_F 1.6986436f          /* sqrt(2*log2(e)); (SCALE*a)·(SCALE*b) = 2*log2(e)*a·b */
#define CS 64                        /* column chunks (grid.y) */
#define CTILE 64                     /* columns staged per LDS tile */
#define BLK_ROWS 256                 /* rows per block (4 waves x 64) */
#define NRB 4                        /* 16-row MFMA blocks per wave */

// ---- prep: normalize rows, scale by sqrt(2log2e) -> bf16 Z; fp32 pos dots; bf16 self-dots ----
__global__ void prep_kernel(const float* __restrict__ zi,
                            const float* __restrict__ zj,
                            __hip_bfloat16* __restrict__ Zb,
                            float* __restrict__ posdot,
                            float* __restrict__ selfarg, int N) {
    int r = blockIdx.x;
    int t = threadIdx.x;  // 0..63, one wave
    const float* pi = zi + (size_t)r * D_DIM;
    const float* pj = zj + (size_t)r * D_DIM;
    float a0 = pi[t], a1 = pi[t + 64];
    float b0 = pj[t], b1 = pj[t + 64];
    float ssi = a0*a0 + a1*a1;
    float ssj = b0*b0 + b1*b1;
    float sij = a0*b0 + a1*b1;
#pragma unroll
    for (int off = 1; off < 64; off <<= 1) {
        ssi += __shfl_xor(ssi, off);
        ssj += __shfl_xor(ssj, off);
        sij += __shfl_xor(sij, off);
    }
    float ni = sqrtf(ssi), nj = sqrtf(ssj);
    float ri = SCALE_F / ni, rj = SCALE_F / nj;
    __hip_bfloat16 vi0 = __float2bfloat16(a0 * ri);
    __hip_bfloat16 vi1 = __float2bfloat16(a1 * ri);
    __hip_bfloat16 vj0 = __float2bfloat16(b0 * rj);
    __hip_bfloat16 vj1 = __float2bfloat16(b1 * rj);
    __hip_bfloat16* zr0 = Zb + (size_t)r * D_DIM;
    __hip_bfloat16* zr1 = Zb + (size_t)(r + N) * D_DIM;
    zr0[t]      = vi0;  zr0[t + 64] = vi1;
    zr1[t]      = vj0;  zr1[t + 64] = vj1;
    // self-dot of the bf16-rounded scaled rows (matches the Gram diagonal to ~1e-6)
    float fi0 = __bfloat162float(vi0), fi1 = __bfloat162float(vi1);
    float fj0 = __bfloat162float(vj0), fj1 = __bfloat162float(vj1);
    float sdi = fi0*fi0 + fi1*fi1;
    float sdj = fj0*fj0 + fj1*fj1;
#pragma unroll
    for (int off = 1; off < 64; off <<= 1) {
        sdi += __shfl_xor(sdi, off);
        sdj += __shfl_xor(sdj, off);
    }
    if (t == 0) {
        posdot[r] = sij / fmaxf(ni * nj, 1e-8f);
        selfarg[r]     = sdi;
        selfarg[r + N] = sdj;
    }
}

// ---- main: fused Gram x exp2 x rowsum (no diag handling; acc is already the exp2 arg) ----
// grid: (N2/BLK_ROWS, CS); block: 256 threads (4 waves, 64 rows each)
__global__ __launch_bounds__(256, 4)
void main_kernel(const ushort* __restrict__ Zu,
                 float* __restrict__ rowpart, int N2) {
    __shared__ ushort tile[CTILE * D_DIM];   // 16 KB, XOR-swizzled 16B slots

    const int tid  = threadIdx.x;
    const int lane = tid & 63;
    const int wave = tid >> 6;
    const int m    = lane & 15;     // tile row (A) / tile col (B) index
    const int kg   = lane >> 4;     // 0..3 k-group
    const int rx   = blockIdx.x;
    const int cy   = blockIdx.y;
    const int rwave0 = rx * BLK_ROWS + wave * 64;

    // A fragments: 4 row-blocks x 4 k-steps, kept in registers (reused across tiles).
    short8 afrag[NRB][4];
#pragma unroll
    for (int rb = 0; rb < NRB; ++rb) {
        const ushort* ap = Zu + (size_t)(rwave0 + rb * 16 + m) * D_DIM + kg * 8;
#pragma unroll
        for (int ks = 0; ks < 4; ++ks)
            afrag[rb][ks] = *(const short8*)(ap + ks * 32);
    }

    float rowacc[NRB][4];
#pragma unroll
    for (int rb = 0; rb < NRB; ++rb)
#pragma unroll
        for (int g = 0; g < 4; ++g) rowacc[rb][g] = 0.0f;

    const int cols_per_chunk = N2 / CS;          // 128
    const int iters = cols_per_chunk / CTILE;    // 2
    const int c0base = cy * cols_per_chunk;

#pragma unroll
    for (int it = 0; it < iters; ++it) {
        const int c0 = c0base + it * CTILE;
        // stage CTILE rows of Z (64 x 256B) with XOR swizzle on 16B slots
#pragma unroll
        for (int i = 0; i < 4; ++i) {
            int chunk = i * 256 + tid;           // 0..1023
            int row   = chunk >> 4;              // 0..63
            int slot  = chunk & 15;              // 16B slot within the row
            int sslot = slot ^ (row & 7);
            *(short8*)&tile[row * D_DIM + sslot * 8] =
                *(const short8*)&Zu[(size_t)(c0 + row) * D_DIM + slot * 8];
        }
        __syncthreads();

#pragma unroll
        for (int sub = 0; sub < 4; ++sub) {
            const int brow = sub * 16 + m;
            short8 bfrag[4];
#pragma unroll
            for (int ks = 0; ks < 4; ++ks) {
                int slot  = ks * 4 + kg;
                int sslot = slot ^ (brow & 7);
                bfrag[ks] = *(const short8*)&tile[brow * D_DIM + sslot * 8];
            }
#pragma unroll
            for (int rb = 0; rb < NRB; ++rb) {
                floatx4 acc = {0.f, 0.f, 0.f, 0.f};
#pragma unroll
                for (int ks = 0; ks < 4; ++ks)
                    acc = __builtin_amdgcn_mfma_f32_16x16x32_bf16(
                        afrag[rb][ks], bfrag[ks], acc, 0, 0, 0);
#pragma unroll
                for (int g = 0; g < 4; ++g)
                    rowacc[rb][g] += exp2f(acc[g]);
            }
        }
        __syncthreads();
    }

    // reduce across the 16 column lanes (m varies within a kg group)
#pragma unroll
    for (int rb = 0; rb < NRB; ++rb)
#pragma unroll
        for (int g = 0; g < 4; ++g) {
            float v = rowacc[rb][g];
            v += __shfl_xor(v, 1);
            v += __shfl_xor(v, 2);
            v += __shfl_xor(v, 4);
            v += __shfl_xor(v, 8);
            if (m == 0) {
                int grow = rwave0 + rb * 16 + kg * 4 + g;
                rowpart[(size_t)cy * N2 + grow] = v;
            }
        }
}

// ---- finalize stage 1: per-row loss, 32-block partial sums ----
__global__ void finalize1_kernel(const float* __restrict__ rowpart,
                                 const float* __restrict__ selfarg,
                                 const float* __restrict__ posdot,
                                 float* __restrict__ bpart, int N2, int NP) {
    __shared__ float red[4];
    int tid = threadIdx.x;                       // 0..255
    int r = blockIdx.x * 256 + tid;              // one row per thread
    float denom = 0.0f;
#pragma unroll
    for (int q = 0; q < CS; ++q) denom += rowpart[(size_t)q * N2 + r];
    denom -= exp2f(selfarg[r]);                  // remove diagonal term
    float pos = posdot[r < NP ? r : r - NP];
    float v = logf(denom) - 2.0f * pos;          // -log(num/denom), 1/t = 2
#pragma unroll
    for (int off = 1; off < 64; off <<= 1) v += __shfl_xor(v, off);
    if ((tid & 63) == 0) red[tid >> 6] = v;
    __syncthreads();
    if (tid == 0) bpart[blockIdx.x] = red[0] + red[1] + red[2] + red[3];
}

// ---- finalize stage 2: mean ----
__global__ void finalize2_kernel(const float* __restrict__ bpart,
                                 float* __restrict__ out, int nb, int N2) {
    int t = threadIdx.x;  // 64
    float v = (t < nb) ? bpart[t] : 0.0f;
#pragma unroll
    for (int off = 1; off < 64; off <<= 1) v += __shfl_xor(v, off);
    if (t == 0) out[0] = v / (float)N2;
}

extern "C" void kernel_launch(void* const* d_in, const int* in_sizes, int n_in,
                              void* d_out, int out_size, void* d_ws, size_t ws_size,
                              hipStream_t stream) {
    const float* zi = (const float*)d_in[0];
    const float* zj = (const float*)d_in[1];
    const int N  = in_sizes[0] / D_DIM;   // 4096
    const int N2 = 2 * N;                 // 8192

    char* w = (char*)d_ws;
    __hip_bfloat16* Zb = (__hip_bfloat16*)w;
    size_t off = (size_t)N2 * D_DIM * sizeof(__hip_bfloat16);        // 2 MB
    float* posdot  = (float*)(w + off);  off += (size_t)N  * sizeof(float);
    float* selfarg = (float*)(w + off);  off += (size_t)N2 * sizeof(float);
    float* rowpart = (float*)(w + off);  off += (size_t)CS * N2 * sizeof(float); // 2 MB
    float* bpart   = (float*)(w + off);

    prep_kernel<<<N, 64, 0, stream>>>(zi, zj, Zb, posdot, selfarg, N);
    dim3 grid(N2 / BLK_ROWS, CS);
    main_kernel<<<grid, 256, 0, stream>>>((const ushort*)Zb, rowpart, N2);
    const int nb = N2 / 256;  // 32
    finalize1_kernel<<<nb, 256, 0, stream>>>(rowpart, selfarg, posdot, bpart, N2, N);
    finalize2_kernel<<<1, 64, 0, stream>>>(bpart, (float*)d_out, nb, N2);
}

// Round 3
// 75.704 us; speedup vs baseline: 1.7522x; 1.7522x over previous
//
#include <hip/hip_runtime.h>
#include <hip/hip_bf16.h>

typedef __attribute__((ext_vector_type(8))) short short8;
typedef __attribute__((ext_vector_type(4))) float floatx4;

#define D_DIM 128
#define SCALE_F 1.6986436f          /* sqrt(2*log2(e)); (SCALE*a)·(SCALE*b) = 2*log2(e)*a·b */
#define CS 16                        /* column chunks (grid.y) */
#define BLK_ROWS 256                 /* rows per block (8 waves x 32 rows) */
#define NRB 2                        /* 16-row MFMA blocks per wave */

// ---- prep: normalize rows, scale by sqrt(2log2e) -> bf16 Z; fp32 pos dots; bf16 self-dots ----
__global__ void prep_kernel(const float* __restrict__ zi,
                            const float* __restrict__ zj,
                            __hip_bfloat16* __restrict__ Zb,
                            float* __restrict__ posdot,
                            float* __restrict__ selfarg, int N) {
    int r = blockIdx.x;
    int t = threadIdx.x;  // 0..63, one wave
    const float* pi = zi + (size_t)r * D_DIM;
    const float* pj = zj + (size_t)r * D_DIM;
    float a0 = pi[t], a1 = pi[t + 64];
    float b0 = pj[t], b1 = pj[t + 64];
    float ssi = a0*a0 + a1*a1;
    float ssj = b0*b0 + b1*b1;
    float sij = a0*b0 + a1*b1;
#pragma unroll
    for (int off = 1; off < 64; off <<= 1) {
        ssi += __shfl_xor(ssi, off);
        ssj += __shfl_xor(ssj, off);
        sij += __shfl_xor(sij, off);
    }
    float ni = sqrtf(ssi), nj = sqrtf(ssj);
    float ri = SCALE_F / ni, rj = SCALE_F / nj;
    __hip_bfloat16 vi0 = __float2bfloat16(a0 * ri);
    __hip_bfloat16 vi1 = __float2bfloat16(a1 * ri);
    __hip_bfloat16 vj0 = __float2bfloat16(b0 * rj);
    __hip_bfloat16 vj1 = __float2bfloat16(b1 * rj);
    __hip_bfloat16* zr0 = Zb + (size_t)r * D_DIM;
    __hip_bfloat16* zr1 = Zb + (size_t)(r + N) * D_DIM;
    zr0[t]      = vi0;  zr0[t + 64] = vi1;
    zr1[t]      = vj0;  zr1[t + 64] = vj1;
    // self-dot of the bf16-rounded scaled rows (matches the Gram diagonal to ~1e-6)
    float fi0 = __bfloat162float(vi0), fi1 = __bfloat162float(vi1);
    float fj0 = __bfloat162float(vj0), fj1 = __bfloat162float(vj1);
    float sdi = fi0*fi0 + fi1*fi1;
    float sdj = fj0*fj0 + fj1*fj1;
#pragma unroll
    for (int off = 1; off < 64; off <<= 1) {
        sdi += __shfl_xor(sdi, off);
        sdj += __shfl_xor(sdj, off);
    }
    if (t == 0) {
        posdot[r] = sij / fmaxf(ni * nj, 1e-8f);
        selfarg[r]     = sdi;
        selfarg[r + N] = sdj;
    }
}

// ---- main: fused Gram x exp2 x rowsum — LDS-free, B read through L1/L2 ----
// grid: (N2/BLK_ROWS, CS); block: 512 threads (8 waves, 32 rows each)
__global__ __launch_bounds__(512, 2)
void main_kernel(const ushort* __restrict__ Zu,
                 float* __restrict__ rowpart, int N2) {
    const int tid  = threadIdx.x;
    const int lane = tid & 63;
    const int wave = tid >> 6;      // 0..7
    const int m    = lane & 15;     // A row / B col index within 16-block
    const int kg   = lane >> 4;     // 0..3 k-group
    const int rwave0 = blockIdx.x * BLK_ROWS + wave * 32;
    const int cy   = blockIdx.y;

    // A fragments: 2 row-blocks x 4 k-steps = 32 VGPRs, loaded once.
    short8 afrag[NRB][4];
#pragma unroll
    for (int rb = 0; rb < NRB; ++rb) {
        const ushort* ap = Zu + (size_t)(rwave0 + rb * 16 + m) * D_DIM + kg * 8;
#pragma unroll
        for (int ks = 0; ks < 4; ++ks)
            afrag[rb][ks] = *(const short8*)(ap + ks * 32);
    }

    float rowacc[NRB][4];
#pragma unroll
    for (int rb = 0; rb < NRB; ++rb)
#pragma unroll
        for (int g = 0; g < 4; ++g) rowacc[rb][g] = 0.0f;

    const int cols_per_chunk = N2 / CS;          // 512
    const int nsub = cols_per_chunk / 16;        // 32
    // per-lane B base: row (c0 + m), k-offset kg*8; advance 16 rows (=2048 ushorts) per sub
    const ushort* bp = Zu + (size_t)(cy * cols_per_chunk + m) * D_DIM + kg * 8;

#pragma unroll 2
    for (int sub = 0; sub < nsub; ++sub) {
        const ushort* bq = bp + (size_t)sub * 16 * D_DIM;
        short8 bfrag[4];
#pragma unroll
        for (int ks = 0; ks < 4; ++ks)
            bfrag[ks] = *(const short8*)(bq + ks * 32);
#pragma unroll
        for (int rb = 0; rb < NRB; ++rb) {
            floatx4 acc = {0.f, 0.f, 0.f, 0.f};
#pragma unroll
            for (int ks = 0; ks < 4; ++ks)
                acc = __builtin_amdgcn_mfma_f32_16x16x32_bf16(
                    afrag[rb][ks], bfrag[ks], acc, 0, 0, 0);
#pragma unroll
            for (int g = 0; g < 4; ++g)
                rowacc[rb][g] += exp2f(acc[g]);
        }
    }

    // reduce across the 16 column lanes (m varies within a kg group)
#pragma unroll
    for (int rb = 0; rb < NRB; ++rb)
#pragma unroll
        for (int g = 0; g < 4; ++g) {
            float v = rowacc[rb][g];
            v += __shfl_xor(v, 1);
            v += __shfl_xor(v, 2);
            v += __shfl_xor(v, 4);
            v += __shfl_xor(v, 8);
            if (m == 0) {
                int grow = rwave0 + rb * 16 + kg * 4 + g;
                rowpart[(size_t)cy * N2 + grow] = v;
            }
        }
}

// ---- finalize stage 1: per-row loss, 32-block partial sums ----
__global__ void finalize1_kernel(const float* __restrict__ rowpart,
                                 const float* __restrict__ selfarg,
                                 const float* __restrict__ posdot,
                                 float* __restrict__ bpart, int N2, int NP) {
    __shared__ float red[4];
    int tid = threadIdx.x;                       // 0..255
    int r = blockIdx.x * 256 + tid;              // one row per thread
    float denom = 0.0f;
#pragma unroll
    for (int q = 0; q < CS; ++q) denom += rowpart[(size_t)q * N2 + r];
    denom -= exp2f(selfarg[r]);                  // remove diagonal term
    float pos = posdot[r < NP ? r : r - NP];
    float v = logf(denom) - 2.0f * pos;          // -log(num/denom), 1/t = 2
#pragma unroll
    for (int off = 1; off < 64; off <<= 1) v += __shfl_xor(v, off);
    if ((tid & 63) == 0) red[tid >> 6] = v;
    __syncthreads();
    if (tid == 0) bpart[blockIdx.x] = red[0] + red[1] + red[2] + red[3];
}

// ---- finalize stage 2: mean ----
__global__ void finalize2_kernel(const float* __restrict__ bpart,
                                 float* __restrict__ out, int nb, int N2) {
    int t = threadIdx.x;  // 64
    float v = (t < nb) ? bpart[t] : 0.0f;
#pragma unroll
    for (int off = 1; off < 64; off <<= 1) v += __shfl_xor(v, off);
    if (t == 0) out[0] = v / (float)N2;
}

extern "C" void kernel_launch(void* const* d_in, const int* in_sizes, int n_in,
                              void* d_out, int out_size, void* d_ws, size_t ws_size,
                              hipStream_t stream) {
    const float* zi = (const float*)d_in[0];
    const float* zj = (const float*)d_in[1];
    const int N  = in_sizes[0] / D_DIM;   // 4096
    const int N2 = 2 * N;                 // 8192

    char* w = (char*)d_ws;
    __hip_bfloat16* Zb = (__hip_bfloat16*)w;
    size_t off = (size_t)N2 * D_DIM * sizeof(__hip_bfloat16);        // 2 MB
    float* posdot  = (float*)(w + off);  off += (size_t)N  * sizeof(float);
    float* selfarg = (float*)(w + off);  off += (size_t)N2 * sizeof(float);
    float* rowpart = (float*)(w + off);  off += (size_t)CS * N2 * sizeof(float); // 512 KB
    float* bpart   = (float*)(w + off);

    prep_kernel<<<N, 64, 0, stream>>>(zi, zj, Zb, posdot, selfarg, N);
    dim3 grid(N2 / BLK_ROWS, CS);
    main_kernel<<<grid, 512, 0, stream>>>((const ushort*)Zb, rowpart, N2);
    const int nb = N2 / 256;  // 32
    finalize1_kernel<<<nb, 256, 0, stream>>>(rowpart, selfarg, posdot, bpart, N2, N);
    finalize2_kernel<<<1, 64, 0, stream>>>(bpart, (float*)d_out, nb, N2);
}

// Round 4
// 46.876 us; speedup vs baseline: 2.8297x; 1.6150x over previous
//
#include <hip/hip_runtime.h>
#include <hip/hip_bf16.h>

typedef __attribute__((ext_vector_type(8))) short short8;
typedef __attribute__((ext_vector_type(4))) float floatx4;

#define D_DIM 128
#define SCALE_F 1.6986436f          /* sqrt(2*log2(e)); (s*a)·(s*b) = 2*log2(e)*a·b */
#define CS 16                        /* column chunks (grid.y) */
#define CTILE 64                     /* columns staged per LDS tile */
#define BLK_ROWS 256                 /* rows per block (4 M-waves x 64 rows) */
#define MREP 4                       /* 16-row MFMA blocks per wave */

// ---- prep: normalize rows, scale by sqrt(2log2e) -> bf16 Z; fp32 pos dots; bf16 self-dots ----
__global__ void prep_kernel(const float* __restrict__ zi,
                            const float* __restrict__ zj,
                            __hip_bfloat16* __restrict__ Zb,
                            float* __restrict__ posdot,
                            float* __restrict__ selfarg, int N) {
    int r = blockIdx.x * 4 + (threadIdx.x >> 6);   // 4 rows per 256-thread block
    int t = threadIdx.x & 63;
    const float* pi = zi + (size_t)r * D_DIM;
    const float* pj = zj + (size_t)r * D_DIM;
    float a0 = pi[t], a1 = pi[t + 64];
    float b0 = pj[t], b1 = pj[t + 64];
    float ssi = a0*a0 + a1*a1;
    float ssj = b0*b0 + b1*b1;
    float sij = a0*b0 + a1*b1;
#pragma unroll
    for (int off = 1; off < 64; off <<= 1) {
        ssi += __shfl_xor(ssi, off);
        ssj += __shfl_xor(ssj, off);
        sij += __shfl_xor(sij, off);
    }
    float ni = sqrtf(ssi), nj = sqrtf(ssj);
    float ri = SCALE_F / ni, rj = SCALE_F / nj;
    __hip_bfloat16 vi0 = __float2bfloat16(a0 * ri);
    __hip_bfloat16 vi1 = __float2bfloat16(a1 * ri);
    __hip_bfloat16 vj0 = __float2bfloat16(b0 * rj);
    __hip_bfloat16 vj1 = __float2bfloat16(b1 * rj);
    __hip_bfloat16* zr0 = Zb + (size_t)r * D_DIM;
    __hip_bfloat16* zr1 = Zb + (size_t)(r + N) * D_DIM;
    zr0[t]      = vi0;  zr0[t + 64] = vi1;
    zr1[t]      = vj0;  zr1[t + 64] = vj1;
    float fi0 = __bfloat162float(vi0), fi1 = __bfloat162float(vi1);
    float fj0 = __bfloat162float(vj0), fj1 = __bfloat162float(vj1);
    float sdi = fi0*fi0 + fi1*fi1;
    float sdj = fj0*fj0 + fj1*fj1;
#pragma unroll
    for (int off = 1; off < 64; off <<= 1) {
        sdi += __shfl_xor(sdi, off);
        sdj += __shfl_xor(sdj, off);
    }
    if (t == 0) {
        posdot[r] = sij / fmaxf(ni * nj, 1e-8f);
        selfarg[r]     = sdi;
        selfarg[r + N] = sdj;
    }
}

// ---- main: fused Gram x exp2 x rowsum ----
// grid (N2/BLK_ROWS, CS); 512 threads = 8 waves: 4 in M (64 rows each) x 2 in N (32-col halves).
// A fragments live in 64 VGPRs, pinned resident via loop-carried asm. B staged in 16 KB LDS.
__global__ __launch_bounds__(512, 4)
void main_kernel(const ushort* __restrict__ Zu,
                 float* __restrict__ rowpart, int N2) {
    __shared__ ushort Btile[CTILE * D_DIM];   // 16 KB, XOR-swizzled 16B slots

    const int tid  = threadIdx.x;
    const int lane = tid & 63;
    const int wave = tid >> 6;      // 0..7
    const int mw   = wave & 3;      // M-wave: which 64-row group
    const int nh   = wave >> 2;     // N-half: which 32 cols of the tile
    const int m    = lane & 15;
    const int kg   = lane >> 4;
    const int rwave0 = blockIdx.x * BLK_ROWS + mw * 64;
    const int cy   = blockIdx.y;

    // A fragments: 4 row-blocks x 4 k-steps = 64 VGPRs, loaded once from global.
    short8 afrag[MREP][4];
#pragma unroll
    for (int rb = 0; rb < MREP; ++rb) {
        const ushort* ap = Zu + (size_t)(rwave0 + rb * 16 + m) * D_DIM + kg * 8;
#pragma unroll
        for (int ks = 0; ks < 4; ++ks)
            afrag[rb][ks] = *(const short8*)(ap + ks * 32);
    }

    float rowacc[MREP][4];
#pragma unroll
    for (int rb = 0; rb < MREP; ++rb)
#pragma unroll
        for (int g = 0; g < 4; ++g) rowacc[rb][g] = 0.0f;

    const int cols_per_chunk = N2 / CS;          // 512
    const int ntile = cols_per_chunk / CTILE;    // 8
    const int c0base = cy * cols_per_chunk;

    for (int t = 0; t < ntile; ++t) {
        const int c0 = c0base + t * CTILE;
        // stage 64 cols x 128 k (16 KB): 1024 16B-chunks over 512 threads
#pragma unroll
        for (int i = 0; i < 2; ++i) {
            int chunk = i * 512 + tid;
            int row   = chunk >> 4;              // 0..63
            int slot  = chunk & 15;
            int ss    = slot ^ (row & 7);
            *(short8*)&Btile[row * D_DIM + ss * 8] =
                *(const short8*)&Zu[(size_t)(c0 + row) * D_DIM + slot * 8];
        }
        __syncthreads();

        // pin A fragments: loop-carried register dependency defeats remat/sinking
#pragma unroll
        for (int rb = 0; rb < MREP; ++rb)
#pragma unroll
            for (int ks = 0; ks < 4; ++ks)
                asm volatile("" : "+v"(afrag[rb][ks]));

#pragma unroll
        for (int s2 = 0; s2 < 2; ++s2) {
            const int brow = nh * 32 + s2 * 16 + m;
            short8 bfrag[4];
#pragma unroll
            for (int ks = 0; ks < 4; ++ks) {
                int ss = (ks * 4 + kg) ^ (brow & 7);
                bfrag[ks] = *(const short8*)&Btile[brow * D_DIM + ss * 8];
            }
#pragma unroll
            for (int rb = 0; rb < MREP; ++rb) {
                floatx4 acc = {0.f, 0.f, 0.f, 0.f};
#pragma unroll
                for (int ks = 0; ks < 4; ++ks)
                    acc = __builtin_amdgcn_mfma_f32_16x16x32_bf16(
                        afrag[rb][ks], bfrag[ks], acc, 0, 0, 0);
#pragma unroll
                for (int g = 0; g < 4; ++g)
                    rowacc[rb][g] += exp2f(acc[g]);
            }
        }
        __syncthreads();
    }

    // reduce across the 16 column lanes; each (cy, nh) writes its own partial slot
#pragma unroll
    for (int rb = 0; rb < MREP; ++rb)
#pragma unroll
        for (int g = 0; g < 4; ++g) {
            float v = rowacc[rb][g];
            v += __shfl_xor(v, 1);
            v += __shfl_xor(v, 2);
            v += __shfl_xor(v, 4);
            v += __shfl_xor(v, 8);
            if (m == 0) {
                int grow = rwave0 + rb * 16 + kg * 4 + g;
                rowpart[(size_t)(cy * 2 + nh) * N2 + grow] = v;
            }
        }
}

// ---- finalize stage 1: per-row loss, 32-block partial sums ----
__global__ void finalize1_kernel(const float* __restrict__ rowpart,
                                 const float* __restrict__ selfarg,
                                 const float* __restrict__ posdot,
                                 float* __restrict__ bpart, int N2, int NP) {
    __shared__ float red[4];
    int tid = threadIdx.x;                       // 0..255
    int r = blockIdx.x * 256 + tid;              // one row per thread
    float denom = 0.0f;
#pragma unroll
    for (int q = 0; q < 2 * CS; ++q) denom += rowpart[(size_t)q * N2 + r];
    denom -= exp2f(selfarg[r]);                  // remove diagonal term
    float pos = posdot[r < NP ? r : r - NP];
    float v = logf(denom) - 2.0f * pos;          // -log(num/denom), 1/t = 2
#pragma unroll
    for (int off = 1; off < 64; off <<= 1) v += __shfl_xor(v, off);
    if ((tid & 63) == 0) red[tid >> 6] = v;
    __syncthreads();
    if (tid == 0) bpart[blockIdx.x] = red[0] + red[1] + red[2] + red[3];
}

// ---- finalize stage 2: mean ----
__global__ void finalize2_kernel(const float* __restrict__ bpart,
                                 float* __restrict__ out, int nb, int N2) {
    int t = threadIdx.x;  // 64
    float v = (t < nb) ? bpart[t] : 0.0f;
#pragma unroll
    for (int off = 1; off < 64; off <<= 1) v += __shfl_xor(v, off);
    if (t == 0) out[0] = v / (float)N2;
}

extern "C" void kernel_launch(void* const* d_in, const int* in_sizes, int n_in,
                              void* d_out, int out_size, void* d_ws, size_t ws_size,
                              hipStream_t stream) {
    const float* zi = (const float*)d_in[0];
    const float* zj = (const float*)d_in[1];
    const int N  = in_sizes[0] / D_DIM;   // 4096
    const int N2 = 2 * N;                 // 8192

    char* w = (char*)d_ws;
    __hip_bfloat16* Zb = (__hip_bfloat16*)w;
    size_t off = (size_t)N2 * D_DIM * sizeof(__hip_bfloat16);        // 2 MB
    float* posdot  = (float*)(w + off);  off += (size_t)N  * sizeof(float);
    float* selfarg = (float*)(w + off);  off += (size_t)N2 * sizeof(float);
    float* rowpart = (float*)(w + off);  off += (size_t)(2 * CS) * N2 * sizeof(float); // 1 MB
    float* bpart   = (float*)(w + off);

    prep_kernel<<<N / 4, 256, 0, stream>>>(zi, zj, Zb, posdot, selfarg, N);
    dim3 grid(N2 / BLK_ROWS, CS);
    main_kernel<<<grid, 512, 0, stream>>>((const ushort*)Zb, rowpart, N2);
    const int nb = N2 / 256;  // 32
    finalize1_kernel<<<nb, 256, 0, stream>>>(rowpart, selfarg, posdot, bpart, N2, N);
    finalize2_kernel<<<1, 64, 0, stream>>>(bpart, (float*)d_out, nb, N2);
}

// Round 5
// 39.506 us; speedup vs baseline: 3.3576x; 1.1865x over previous
//
#include <hip/hip_runtime.h>
#include <hip/hip_bf16.h>

typedef __attribute__((ext_vector_type(8))) short short8;
typedef __attribute__((ext_vector_type(4))) float floatx4;

#define D_DIM 128
#define SCALE_F 1.6986436f          /* sqrt(2*log2(e)); (s*a)·(s*b) = 2*log2(e)*a·b */
#define CS 16                        /* column chunks (grid.y) */
#define CTILE 64                     /* columns staged per LDS tile */
#define BLK_ROWS 256                 /* rows per block (4 M-waves x 64 rows) */
#define MREP 4                       /* 16-row MFMA blocks per wave */

// ---- prep: normalize rows, scale by sqrt(2log2e) -> bf16 Z; fp32 pos dots; bf16 self-dots ----
__global__ void prep_kernel(const float* __restrict__ zi,
                            const float* __restrict__ zj,
                            __hip_bfloat16* __restrict__ Zb,
                            float* __restrict__ posdot,
                            float* __restrict__ selfarg, int N) {
    int r = blockIdx.x * 4 + (threadIdx.x >> 6);   // 4 rows per 256-thread block
    int t = threadIdx.x & 63;
    const float* pi = zi + (size_t)r * D_DIM;
    const float* pj = zj + (size_t)r * D_DIM;
    float a0 = pi[t], a1 = pi[t + 64];
    float b0 = pj[t], b1 = pj[t + 64];
    float ssi = a0*a0 + a1*a1;
    float ssj = b0*b0 + b1*b1;
    float sij = a0*b0 + a1*b1;
#pragma unroll
    for (int off = 1; off < 64; off <<= 1) {
        ssi += __shfl_xor(ssi, off);
        ssj += __shfl_xor(ssj, off);
        sij += __shfl_xor(sij, off);
    }
    float ni = sqrtf(ssi), nj = sqrtf(ssj);
    float ri = SCALE_F / ni, rj = SCALE_F / nj;
    __hip_bfloat16 vi0 = __float2bfloat16(a0 * ri);
    __hip_bfloat16 vi1 = __float2bfloat16(a1 * ri);
    __hip_bfloat16 vj0 = __float2bfloat16(b0 * rj);
    __hip_bfloat16 vj1 = __float2bfloat16(b1 * rj);
    __hip_bfloat16* zr0 = Zb + (size_t)r * D_DIM;
    __hip_bfloat16* zr1 = Zb + (size_t)(r + N) * D_DIM;
    zr0[t]      = vi0;  zr0[t + 64] = vi1;
    zr1[t]      = vj0;  zr1[t + 64] = vj1;
    float fi0 = __bfloat162float(vi0), fi1 = __bfloat162float(vi1);
    float fj0 = __bfloat162float(vj0), fj1 = __bfloat162float(vj1);
    float sdi = fi0*fi0 + fi1*fi1;
    float sdj = fj0*fj0 + fj1*fj1;
#pragma unroll
    for (int off = 1; off < 64; off <<= 1) {
        sdi += __shfl_xor(sdi, off);
        sdj += __shfl_xor(sdj, off);
    }
    if (t == 0) {
        posdot[r] = sij / fmaxf(ni * nj, 1e-8f);
        selfarg[r]     = sdi;
        selfarg[r + N] = sdj;
    }
}

// ---- main: fused Gram x exp2 x rowsum ----
// grid (N2/BLK_ROWS, CS); 512 threads = 8 waves: 4 in M (64 rows each) x 2 in N (32-col halves).
// A fragments live in 64 VGPRs, pinned resident via loop-carried asm. B staged in 16 KB LDS.
// exp via native v_exp_f32 (arg bounded by 2*log2e ~= 2.89 -- no range reduction needed).
__global__ __launch_bounds__(512, 4)
void main_kernel(const ushort* __restrict__ Zu,
                 float* __restrict__ rowpart, int N2) {
    __shared__ ushort Btile[CTILE * D_DIM];   // 16 KB, XOR-swizzled 16B slots

    const int tid  = threadIdx.x;
    const int lane = tid & 63;
    const int wave = tid >> 6;      // 0..7
    const int mw   = wave & 3;      // M-wave: which 64-row group
    const int nh   = wave >> 2;     // N-half: which 32 cols of the tile
    const int m    = lane & 15;
    const int kg   = lane >> 4;
    const int rwave0 = blockIdx.x * BLK_ROWS + mw * 64;
    const int cy   = blockIdx.y;

    // A fragments: 4 row-blocks x 4 k-steps = 64 VGPRs, loaded once from global.
    short8 afrag[MREP][4];
#pragma unroll
    for (int rb = 0; rb < MREP; ++rb) {
        const ushort* ap = Zu + (size_t)(rwave0 + rb * 16 + m) * D_DIM + kg * 8;
#pragma unroll
        for (int ks = 0; ks < 4; ++ks)
            afrag[rb][ks] = *(const short8*)(ap + ks * 32);
    }

    float rowacc[MREP][4];
#pragma unroll
    for (int rb = 0; rb < MREP; ++rb)
#pragma unroll
        for (int g = 0; g < 4; ++g) rowacc[rb][g] = 0.0f;

    const int cols_per_chunk = N2 / CS;          // 512
    const int ntile = cols_per_chunk / CTILE;    // 8
    const int c0base = cy * cols_per_chunk;

    for (int t = 0; t < ntile; ++t) {
        const int c0 = c0base + t * CTILE;
        // stage 64 cols x 128 k (16 KB): 1024 16B-chunks over 512 threads
#pragma unroll
        for (int i = 0; i < 2; ++i) {
            int chunk = i * 512 + tid;
            int row   = chunk >> 4;              // 0..63
            int slot  = chunk & 15;
            int ss    = slot ^ (row & 7);
            *(short8*)&Btile[row * D_DIM + ss * 8] =
                *(const short8*)&Zu[(size_t)(c0 + row) * D_DIM + slot * 8];
        }
        __syncthreads();

        // pin A fragments: loop-carried register dependency defeats remat/sinking
#pragma unroll
        for (int rb = 0; rb < MREP; ++rb)
#pragma unroll
            for (int ks = 0; ks < 4; ++ks)
                asm volatile("" : "+v"(afrag[rb][ks]));

#pragma unroll
        for (int s2 = 0; s2 < 2; ++s2) {
            const int brow = nh * 32 + s2 * 16 + m;
            short8 bfrag[4];
#pragma unroll
            for (int ks = 0; ks < 4; ++ks) {
                int ss = (ks * 4 + kg) ^ (brow & 7);
                bfrag[ks] = *(const short8*)&Btile[brow * D_DIM + ss * 8];
            }
#pragma unroll
            for (int rb = 0; rb < MREP; ++rb) {
                floatx4 acc = {0.f, 0.f, 0.f, 0.f};
#pragma unroll
                for (int ks = 0; ks < 4; ++ks)
                    acc = __builtin_amdgcn_mfma_f32_16x16x32_bf16(
                        afrag[rb][ks], bfrag[ks], acc, 0, 0, 0);
#pragma unroll
                for (int g = 0; g < 4; ++g)
                    rowacc[rb][g] += __builtin_amdgcn_exp2f(acc[g]);
            }
        }
        __syncthreads();
    }

    // reduce across the 16 column lanes; each (cy, nh) writes its own partial slot
#pragma unroll
    for (int rb = 0; rb < MREP; ++rb)
#pragma unroll
        for (int g = 0; g < 4; ++g) {
            float v = rowacc[rb][g];
            v += __shfl_xor(v, 1);
            v += __shfl_xor(v, 2);
            v += __shfl_xor(v, 4);
            v += __shfl_xor(v, 8);
            if (m == 0) {
                int grow = rwave0 + rb * 16 + kg * 4 + g;
                rowpart[(size_t)(cy * 2 + nh) * N2 + grow] = v;
            }
        }
}

// ---- finalize stage 1: per-row loss, 32-block partial sums ----
__global__ void finalize1_kernel(const float* __restrict__ rowpart,
                                 const float* __restrict__ selfarg,
                                 const float* __restrict__ posdot,
                                 float* __restrict__ bpart, int N2, int NP) {
    __shared__ float red[4];
    int tid = threadIdx.x;                       // 0..255
    int r = blockIdx.x * 256 + tid;              // one row per thread
    float denom = 0.0f;
#pragma unroll
    for (int q = 0; q < 2 * CS; ++q) denom += rowpart[(size_t)q * N2 + r];
    denom -= __builtin_amdgcn_exp2f(selfarg[r]); // remove diagonal term
    float pos = posdot[r < NP ? r : r - NP];
    float v = logf(denom) - 2.0f * pos;          // -log(num/denom), 1/t = 2
#pragma unroll
    for (int off = 1; off < 64; off <<= 1) v += __shfl_xor(v, off);
    if ((tid & 63) == 0) red[tid >> 6] = v;
    __syncthreads();
    if (tid == 0) bpart[blockIdx.x] = red[0] + red[1] + red[2] + red[3];
}

// ---- finalize stage 2: mean ----
__global__ void finalize2_kernel(const float* __restrict__ bpart,
                                 float* __restrict__ out, int nb, int N2) {
    int t = threadIdx.x;  // 64
    float v = (t < nb) ? bpart[t] : 0.0f;
#pragma unroll
    for (int off = 1; off < 64; off <<= 1) v += __shfl_xor(v, off);
    if (t == 0) out[0] = v / (float)N2;
}

extern "C" void kernel_launch(void* const* d_in, const int* in_sizes, int n_in,
                              void* d_out, int out_size, void* d_ws, size_t ws_size,
                              hipStream_t stream) {
    const float* zi = (const float*)d_in[0];
    const float* zj = (const float*)d_in[1];
    const int N  = in_sizes[0] / D_DIM;   // 4096
    const int N2 = 2 * N;                 // 8192

    char* w = (char*)d_ws;
    __hip_bfloat16* Zb = (__hip_bfloat16*)w;
    size_t off = (size_t)N2 * D_DIM * sizeof(__hip_bfloat16);        // 2 MB
    float* posdot  = (float*)(w + off);  off += (size_t)N  * sizeof(float);
    float* selfarg = (float*)(w + off);  off += (size_t)N2 * sizeof(float);
    float* rowpart = (float*)(w + off);  off += (size_t)(2 * CS) * N2 * sizeof(float); // 1 MB
    float* bpart   = (float*)(w + off);

    prep_kernel<<<N / 4, 256, 0, stream>>>(zi, zj, Zb, posdot, selfarg, N);
    dim3 grid(N2 / BLK_ROWS, CS);
    main_kernel<<<grid, 512, 0, stream>>>((const ushort*)Zb, rowpart, N2);
    const int nb = N2 / 256;  // 32
    finalize1_kernel<<<nb, 256, 0, stream>>>(rowpart, selfarg, posdot, bpart, N2, N);
    finalize2_kernel<<<1, 64, 0, stream>>>(bpart, (float*)d_out, nb, N2);
}